// Round 1
// baseline (653.444 us; speedup 1.0000x reference)
//
#include <hip/hip_runtime.h>
#include <math.h>

// GASLayer: per-column EMA normalization with chunked parallel scan.
// T=32768 rows, D=1024 cols. C=512 chunks of L=64 rows.
// Each K1/K3 thread owns 4 consecutive columns (float4 lanes).
// ws layout (floats, n = C*D = 524288 each):
//   [0] sum, [1] sumsq, [2] B_mu, [3] Q0, [4] Q1, [5] mu_in, [6] var_in
// (Q2 is data-independent -> host constant.)
// Total ws use: 7 * 524288 * 4 B = 14 MiB.

#define T_DIM 32768
#define D_DIM 1024
#define CHUNK 512
#define CLEN  (T_DIM / CHUNK)   // 64
#define ETA_MU_F 0.01f
#define ETA_VAR_F 0.02f

typedef float vf4 __attribute__((ext_vector_type(4)));

// K1: one block per chunk; thread j handles columns 4j..4j+3.
// mu_k = a^{k+1} * mu_in + m_k  (m = zero-init run), p_k = a^{k+1}
// var_out = b^L var_in + Q0 + Q1*mu_in + Q2*mu_in^2   (Q2 host-side)
__global__ __launch_bounds__(256) void k_chunk_summary(
    const float* __restrict__ x, float* __restrict__ ws) {
    const int c = blockIdx.x;
    const int j = threadIdx.x;                  // column group [0,256)
    const int n = CHUNK * D_DIM;
    const float a = 1.0f - ETA_MU_F;
    const float b = 1.0f - ETA_VAR_F;

    vf4 s  = {0.0f, 0.0f, 0.0f, 0.0f};
    vf4 s2 = {0.0f, 0.0f, 0.0f, 0.0f};
    vf4 m  = {0.0f, 0.0f, 0.0f, 0.0f};
    vf4 q0 = {0.0f, 0.0f, 0.0f, 0.0f};
    vf4 q1 = {0.0f, 0.0f, 0.0f, 0.0f};
    float p = 1.0f;

    const vf4* xp = (const vf4*)(x + (size_t)c * CLEN * D_DIM) + j;
#pragma unroll 8
    for (int k = 0; k < CLEN; ++k) {
        vf4 xv = xp[(size_t)k * (D_DIM / 4)];
        p *= a;                                  // p = a^{k+1}
        s  += xv;
        s2 += xv * xv;
        m  += ETA_MU_F * (xv - m);               // same arithmetic form as replay
        vf4 dv = xv - m;
        q0 = b * q0 + ETA_VAR_F * (dv * dv);
        q1 = b * q1 - (2.0f * ETA_VAR_F * p) * dv;
    }
    const int base = c * D_DIM + 4 * j;
    *(vf4*)(ws + 0 * n + base) = s;
    *(vf4*)(ws + 1 * n + base) = s2;
    *(vf4*)(ws + 2 * n + base) = m;
    *(vf4*)(ws + 3 * n + base) = q0;
    *(vf4*)(ws + 4 * n + base) = q1;
}

// K2: per-column. Reduce partials -> mu0, std0 (reference stores STD in the
// var slot initially), then scan the C chunk summaries to get entry states.
// 16 blocks x 64 threads so the latency-bound scan spreads over 16 CUs.
__global__ __launch_bounds__(64) void k_scan(
    float* __restrict__ ws, float a_pow, float b_pow, float q2c) {
    const int d = blockIdx.x * 64 + threadIdx.x;   // [0, D)
    const int n = CHUNK * D_DIM;
    const float* sum  = ws + 0 * n;
    const float* sum2 = ws + 1 * n;
    const float* bmu  = ws + 2 * n;
    const float* q0   = ws + 3 * n;
    const float* q1   = ws + 4 * n;
    float* mu_in  = ws + 5 * n;
    float* var_in = ws + 6 * n;

    float s = 0.0f, s2 = 0.0f;
#pragma unroll 8
    for (int c = 0; c < CHUNK; ++c) {
        s  += sum[c * D_DIM + d];
        s2 += sum2[c * D_DIM + d];
    }
    float mu0 = s / (float)T_DIM;
    float v0  = (s2 - (float)T_DIM * mu0 * mu0) / (float)(T_DIM - 1);
    float std0 = sqrtf(fmaxf(v0, 0.0f));

    float mu = mu0;
    float var = std0;   // NOTE: std, not variance — matches reference
#pragma unroll 4
    for (int c = 0; c < CHUNK; ++c) {
        int idx = c * D_DIM + d;
        mu_in[idx]  = mu;
        var_in[idx] = var;
        float mu_next = a_pow * mu + bmu[idx];
        var = b_pow * var + q0[idx] + mu * (q1[idx] + q2c * mu);
        mu = mu_next;
    }
}

// K3: replay each chunk with exact reference arithmetic, write outputs.
// Non-temporal stores keep x resident in L3 for this second pass.
__global__ __launch_bounds__(256) void k_replay(
    const float* __restrict__ x, const float* __restrict__ ws,
    float* __restrict__ out) {
    const int c = blockIdx.x;
    const int j = threadIdx.x;                  // column group [0,256)
    const int n = CHUNK * D_DIM;
    const int base = c * D_DIM + 4 * j;

    vf4 mu  = *(const vf4*)(ws + 5 * n + base);
    vf4 var = *(const vf4*)(ws + 6 * n + base);

    const size_t t0 = (size_t)c * CLEN;
    const vf4* xp = (const vf4*)(x + t0 * D_DIM) + j;
    vf4* norm_out = (vf4*)(out + t0 * D_DIM) + j;
    float* info_base = out + (size_t)T_DIM * D_DIM + t0 * (2 * D_DIM);
    vf4* mu_out  = (vf4*)(info_base) + j;
    vf4* var_out = (vf4*)(info_base + D_DIM) + j;

#pragma unroll 4
    for (int k = 0; k < CLEN; ++k) {
        vf4 xv = xp[(size_t)k * (D_DIM / 4)];
        mu += ETA_MU_F * (xv - mu);
        vf4 diff = xv - mu;
        var = (1.0f - ETA_VAR_F) * var + ETA_VAR_F * (diff * diff);
        vf4 nrm;
        nrm.x = diff.x / sqrtf(var.x);
        nrm.y = diff.y / sqrtf(var.y);
        nrm.z = diff.z / sqrtf(var.z);
        nrm.w = diff.w / sqrtf(var.w);
        __builtin_nontemporal_store(nrm, norm_out + (size_t)k * (D_DIM / 4));
        __builtin_nontemporal_store(mu,  mu_out  + (size_t)k * (2 * D_DIM / 4));
        __builtin_nontemporal_store(var, var_out + (size_t)k * (2 * D_DIM / 4));
    }
}

extern "C" void kernel_launch(void* const* d_in, const int* in_sizes, int n_in,
                              void* d_out, int out_size, void* d_ws, size_t ws_size,
                              hipStream_t stream) {
    const float* x = (const float*)d_in[0];
    float* out = (float*)d_out;
    float* ws = (float*)d_ws;

    // Constant decay-over-chunk factors, computed in double on host.
    float a_pow = (float)pow(1.0 - 0.01, (double)CLEN);  // 0.99^64
    float b_pow = (float)pow(1.0 - 0.02, (double)CLEN);  // 0.98^64

    // Q2 = sum_{k=0}^{L-1} b^{L-1-k} * eta_var * a^{2(k+1)}  (data-independent)
    double q2d = 0.0;
    for (int k = 0; k < CLEN; ++k) {
        double pk = pow(0.99, (double)(k + 1));
        q2d = 0.98 * q2d + 0.02 * pk * pk;
    }
    float q2c = (float)q2d;

    hipLaunchKernelGGL(k_chunk_summary, dim3(CHUNK), dim3(256), 0, stream, x, ws);
    hipLaunchKernelGGL(k_scan, dim3(D_DIM / 64), dim3(64), 0, stream, ws, a_pow, b_pow, q2c);
    hipLaunchKernelGGL(k_replay, dim3(CHUNK), dim3(256), 0, stream, x, ws, out);
}